// Round 2
// baseline (514.713 us; speedup 1.0000x reference)
//
#include <hip/hip_runtime.h>

// HeteroRGCN forward, MI355X. Structure (rounds 1-6):
//  - Only h2["target"] matters => layer1 etypes 1,3; layer2 etypes 0,2. x_card/x_ip dead.
//  - Layer1 aggregate-first; layer2+output folded to Wfold=W2@wout (2 cols/node).
//  - bf16 storage + MFMA 16x16x32 for the 128x128 transform; fp32 accumulate.
//  - Round 4: single-atomic CSR build, CSR-gather target side.
//  - Round 5: global-atomic hist replaced by partitioned LDS histogram (zero global atomics).
//  - Round 6: hist split into its OWN kernel — the 32KB static LDS was poisoning the
//    occupancy of the fused streaming blocks (74%->34%, round-5 regression). NCHUNK 8->4
//    halves per-chunk hist traffic. front_k is now LDS-free pure streaming.

#define NT 200000
#define NCARD 100000
#define NIP 100000
#define NE 300000

#define RANGE 8192       // bins per hist block (32KB LDS)
#define NCHUNK 4
#define CHUNK 75000      // NE / NCHUNK
#define RB1 13           // ceil(NCARD/RANGE)
#define RB3 13
#define RB0 25           // ceil(NT/RANGE)
#define RB2 25
#define NB_HISTA ((RB1 + RB3 + RB0 + RB2) * NCHUNK)  // 304

typedef __attribute__((ext_vector_type(8))) short s8v;   // 8 bf16 (4 VGPRs)
typedef __attribute__((ext_vector_type(4))) float f4v;   // mfma accumulator

__device__ __forceinline__ unsigned short f2b(float f) {
  unsigned u = __float_as_uint(f);
  u = (u + 0x7fff + ((u >> 16) & 1)) >> 16;  // RNE (finite inputs)
  return (unsigned short)u;
}

// ---------------- LDS histogram + per-edge rank (4 relations x NCHUNK chunks) ----------------
// Each block: one 8192-bin dst range x one edge chunk. LDS atomics only; dst arrays are
// 4.8MB total -> L2/L3-resident across the RB-fold re-reads.

__global__ void hist_k(const int* __restrict__ d1, const int* __restrict__ d3,
                       const int* __restrict__ d0, const int* __restrict__ d2,
                       int* __restrict__ h1, int* __restrict__ h3,
                       int* __restrict__ h0, int* __restrict__ h2,
                       int* __restrict__ rk1, int* __restrict__ rk3,
                       int* __restrict__ rk0, int* __restrict__ rk2) {
  __shared__ int hsh[RANGE];
  int tid = threadIdx.x;
  int rb = blockIdx.x / NCHUNK, c = blockIdx.x % NCHUNK;
  const int* d; int* hist; int* rkl; int N; int lo;
  if (rb < RB1) { d = d1; hist = h1; rkl = rk1; N = NCARD; lo = rb * RANGE; }
  else if (rb < RB1 + RB3) { d = d3; hist = h3; rkl = rk3; N = NIP; lo = (rb - RB1) * RANGE; }
  else if (rb < RB1 + RB3 + RB0) { d = d0; hist = h0; rkl = rk0; N = NT; lo = (rb - RB1 - RB3) * RANGE; }
  else { d = d2; hist = h2; rkl = rk2; N = NT; lo = (rb - RB1 - RB3 - RB0) * RANGE; }
  for (int b = tid; b < RANGE; b += 256) hsh[b] = 0;
  __syncthreads();
  int e1 = (c + 1) * CHUNK;
  for (int e = c * CHUNK + tid; e < e1; e += 256) {
    int key = d[e] - lo;
    if ((unsigned)key < (unsigned)RANGE) rkl[e] = atomicAdd(&hsh[key], 1);
  }
  __syncthreads();
  for (int b = tid; b < RANGE; b += 256) {
    int g = lo + b;
    if (g < N) hist[(size_t)c * N + g] = hsh[b];
  }
}

// ---------------- fused front: W1 transpose | Wfold prep | cvt (LDS-free streaming) ----------
// Block ranges: [0,128) wt, [128] prep, [129,12629) cvt (2 float4/thread).

#define NB_WT 128
#define NB_CVT 12500     // NT*128/4 float4s / 512 per block

__global__ void front_k(const float* __restrict__ x, const float* __restrict__ w1,
                        const float* __restrict__ w2, const float* __restrict__ b2,
                        const float* __restrict__ wout,
                        unsigned short* __restrict__ xb, unsigned short* __restrict__ wtC,
                        unsigned short* __restrict__ wtI, float* __restrict__ wfC,
                        float* __restrict__ wfI, float* __restrict__ bfC,
                        float* __restrict__ bfI) {
  int bid = blockIdx.x, tid = threadIdx.x;
  if (bid < NB_WT) {
    int t = bid * 256 + tid;  // 32768
    int r = t >> 14;
    int n = (t >> 7) & 127, k = t & 127;
    const float* src = w1 + (r ? 3 : 1) * 16384;
    unsigned short* dst = r ? wtI : wtC;
    dst[n * 128 + k] = f2b(src[k * 128 + n]);
  } else if (bid == NB_WT) {
    int k = tid >> 1, o = tid & 1;
    float sC = 0.f, sI = 0.f;
    for (int j = 0; j < 128; j++) {
      float wo = wout[j * 2 + o];
      sC += w2[0 * 16384 + k * 128 + j] * wo;
      sI += w2[2 * 16384 + k * 128 + j] * wo;
    }
    wfC[k * 2 + o] = sC;
    wfI[k * 2 + o] = sI;
    if (tid < 2) {
      float s = 0.f;
      for (int j = 0; j < 128; j++) s += b2[0 * 128 + j] * wout[j * 2 + tid];
      bfC[tid] = s;
    } else if (tid < 4) {
      int oo = tid - 2;
      float s = 0.f;
      for (int j = 0; j < 128; j++) s += b2[2 * 128 + j] * wout[j * 2 + oo];
      bfI[oo] = s;
    }
  } else {
    long i = (long)(bid - (NB_WT + 1)) * 512 + tid;  // two float4 each
    const float4* x4 = (const float4*)x;
    float4 va = x4[i];
    float4 vb = x4[i + 256];
    uint2 oa, ob;
    oa.x = (unsigned)f2b(va.x) | ((unsigned)f2b(va.y) << 16);
    oa.y = (unsigned)f2b(va.z) | ((unsigned)f2b(va.w) << 16);
    ob.x = (unsigned)f2b(vb.x) | ((unsigned)f2b(vb.y) << 16);
    ob.y = (unsigned)f2b(vb.z) | ((unsigned)f2b(vb.w) << 16);
    ((uint2*)xb)[i] = oa;
    ((uint2*)xb)[i + 256] = ob;
  }
}

// -------- scans: fold per-chunk hist -> (deg, chunk-exclusive prefix), then block scan -------

__global__ void scan1q_k(int* __restrict__ h1, int* __restrict__ deg1,
                         int* __restrict__ off1, int* __restrict__ bs1, int nb1,
                         int* __restrict__ h3, int* __restrict__ deg3,
                         int* __restrict__ off3, int* __restrict__ bs3, int nb3,
                         int* __restrict__ h0, int* __restrict__ deg0,
                         int* __restrict__ off0, int* __restrict__ bs0, int nb0,
                         int* __restrict__ h2, int* __restrict__ deg2,
                         int* __restrict__ off2, int* __restrict__ bs2) {
  __shared__ int s[256];
  int bid = blockIdx.x;
  int* hist; int* deg; int* off; int* bsum; int N; int lb;
  if (bid < nb1) { hist = h1; deg = deg1; off = off1; bsum = bs1; N = NCARD; lb = bid; }
  else if (bid < nb1 + nb3) { hist = h3; deg = deg3; off = off3; bsum = bs3; N = NIP; lb = bid - nb1; }
  else if (bid < nb1 + nb3 + nb0) { hist = h0; deg = deg0; off = off0; bsum = bs0; N = NT; lb = bid - nb1 - nb3; }
  else { hist = h2; deg = deg2; off = off2; bsum = bs2; N = NT; lb = bid - nb1 - nb3 - nb0; }
  int tid = threadIdx.x;
  int i = lb * 256 + tid;
  int v = 0;
  if (i < N) {
    int acc = 0;
#pragma unroll
    for (int c = 0; c < NCHUNK; c++) {
      size_t idx = (size_t)c * N + i;
      int t = hist[idx];
      hist[idx] = acc;  // chunk-exclusive prefix for fill
      acc += t;
    }
    deg[i] = acc;
    v = acc;
  }
  s[tid] = v;
  __syncthreads();
  for (int o = 1; o < 256; o <<= 1) {
    int t = (tid >= o) ? s[tid - o] : 0;
    __syncthreads();
    s[tid] += t;
    __syncthreads();
  }
  if (i < N) off[i] = s[tid] - v;
  if (tid == 255) bsum[lb] = s[255];
}

__global__ void scan2q_k(int* __restrict__ bs1, int nb1, int* __restrict__ bs3, int nb3,
                         int* __restrict__ bs0, int nb0, int* __restrict__ bs2, int nb2) {
  __shared__ int s[1024];
  int* bs; int nb;
  if (blockIdx.x == 0) { bs = bs1; nb = nb1; }
  else if (blockIdx.x == 1) { bs = bs3; nb = nb3; }
  else if (blockIdx.x == 2) { bs = bs0; nb = nb0; }
  else { bs = bs2; nb = nb2; }
  int t = threadIdx.x;
  int v = (t < nb) ? bs[t] : 0;
  s[t] = v;
  __syncthreads();
  for (int o = 1; o < 1024; o <<= 1) {
    int u = (t >= o) ? s[t - o] : 0;
    __syncthreads();
    s[t] += u;
    __syncthreads();
  }
  if (t < nb) bs[t] = s[t] - v;
}

__global__ void scan3q_k(int* __restrict__ off1, const int* __restrict__ bs1, int nb1,
                         int* __restrict__ off3, const int* __restrict__ bs3, int nb3,
                         int* __restrict__ off0, const int* __restrict__ bs0, int nb0,
                         int* __restrict__ off2, const int* __restrict__ bs2) {
  int bid = blockIdx.x;
  int* off; const int* bsum; int N; int lb;
  if (bid < nb1) { off = off1; bsum = bs1; N = NCARD; lb = bid; }
  else if (bid < nb1 + nb3) { off = off3; bsum = bs3; N = NIP; lb = bid - nb1; }
  else if (bid < nb1 + nb3 + nb0) { off = off0; bsum = bs0; N = NT; lb = bid - nb1 - nb3; }
  else { off = off2; bsum = bs2; N = NT; lb = bid - nb1 - nb3 - nb0; }
  int i = lb * 256 + threadIdx.x;
  if (i < N) off[i] += bsum[lb];
}

// ------- atomic-free CSR fill: slot = off[dst] + chunkpref[c][dst] + rank_local -------

__global__ void fill4_k(const int* __restrict__ s1, const int* __restrict__ d1,
                        const int* __restrict__ rk1, const int* __restrict__ off1,
                        const int* __restrict__ h1, int* __restrict__ csr1,
                        const int* __restrict__ s3, const int* __restrict__ d3,
                        const int* __restrict__ rk3, const int* __restrict__ off3,
                        const int* __restrict__ h3, int* __restrict__ csr3,
                        const int* __restrict__ s0, const int* __restrict__ d0,
                        const int* __restrict__ rk0, const int* __restrict__ off0,
                        const int* __restrict__ h0, int* __restrict__ csr0,
                        const int* __restrict__ s2, const int* __restrict__ d2,
                        const int* __restrict__ rk2, const int* __restrict__ off2,
                        const int* __restrict__ h2, int* __restrict__ csr2) {
  int t = blockIdx.x * 256 + threadIdx.x;
  if (t < NE) {
    int e = t, c = e / CHUNK, dd = d1[e];
    csr1[off1[dd] + h1[(size_t)c * NCARD + dd] + rk1[e]] = s1[e];
  } else if (t < 2 * NE) {
    int e = t - NE, c = e / CHUNK, dd = d3[e];
    csr3[off3[dd] + h3[(size_t)c * NIP + dd] + rk3[e]] = s3[e];
  } else if (t < 3 * NE) {
    int e = t - 2 * NE, c = e / CHUNK, dd = d0[e];
    csr0[off0[dd] + h0[(size_t)c * NT + dd] + rk0[e]] = s0[e];
  } else if (t < 4 * NE) {
    int e = t - 3 * NE, c = e / CHUNK, dd = d2[e];
    csr2[off2[dd] + h2[(size_t)c * NT + dd] + rk2[e]] = s2[e];
  }
}

// ------- layer1 source aggregation: one wave per dst row -------
// 4 edge-groups x 16 feature-lanes (16B each); shfl_xor reduce across groups.

__global__ void aggf_k(const unsigned short* __restrict__ xb,
                       const int* __restrict__ off1, const int* __restrict__ deg1,
                       const int* __restrict__ csr1, unsigned short* __restrict__ accC,
                       const int* __restrict__ off3, const int* __restrict__ deg3,
                       const int* __restrict__ csr3, unsigned short* __restrict__ accI) {
  int w = (blockIdx.x * 256 + threadIdx.x) >> 6;
  int lane = threadIdx.x & 63;
  if (w >= NCARD + NIP) return;
  const int* off; const int* deg; const int* csr; unsigned short* acc; int row;
  if (w < NCARD) { off = off1; deg = deg1; csr = csr1; acc = accC; row = w; }
  else { off = off3; deg = deg3; csr = csr3; acc = accI; row = w - NCARD; }
  int start = off[row], cnt = deg[row];
  int eg = lane >> 4, fl = lane & 15;
  float a[8] = {0.f, 0.f, 0.f, 0.f, 0.f, 0.f, 0.f, 0.f};
  for (int i = eg; i < cnt; i += 4) {
    int s = csr[start + i];
    uint4 v = *(const uint4*)(xb + (size_t)s * 128 + fl * 8);
    a[0] += __uint_as_float(v.x << 16);
    a[1] += __uint_as_float(v.x & 0xffff0000u);
    a[2] += __uint_as_float(v.y << 16);
    a[3] += __uint_as_float(v.y & 0xffff0000u);
    a[4] += __uint_as_float(v.z << 16);
    a[5] += __uint_as_float(v.z & 0xffff0000u);
    a[6] += __uint_as_float(v.w << 16);
    a[7] += __uint_as_float(v.w & 0xffff0000u);
  }
#pragma unroll
  for (int j = 0; j < 8; j++) {
    a[j] += __shfl_xor(a[j], 16);
    a[j] += __shfl_xor(a[j], 32);
  }
  if (eg == 0) {
    uint4 o;
    o.x = (unsigned)f2b(a[0]) | ((unsigned)f2b(a[1]) << 16);
    o.y = (unsigned)f2b(a[2]) | ((unsigned)f2b(a[3]) << 16);
    o.z = (unsigned)f2b(a[4]) | ((unsigned)f2b(a[5]) << 16);
    o.w = (unsigned)f2b(a[6]) | ((unsigned)f2b(a[7]) << 16);
    *(uint4*)(acc + (size_t)row * 128 + fl * 8) = o;
  }
}

// ------- layer1 transform via MFMA + leaky + fold-to-z epilogue -------
// Per wave: 32 rows x 128 cols, K=128. C/D layout: col=lane&15, row=(lane>>4)*4+reg.
// A layout: A[m=lane&15][k=(lane>>4)*8+j].

__global__ __launch_bounds__(256) void gemm_mfma_k(
    const unsigned short* __restrict__ accC, const unsigned short* __restrict__ accI,
    const unsigned short* __restrict__ wtC, const unsigned short* __restrict__ wtI,
    const float* __restrict__ b1, const int* __restrict__ deg1,
    const int* __restrict__ deg3, const float* __restrict__ wfC,
    const float* __restrict__ wfI, const float* __restrict__ bfC,
    const float* __restrict__ bfI, float* __restrict__ zc, float* __restrict__ zi,
    int gbC) {
  int bid = blockIdx.x;
  const unsigned short* accb; const unsigned short* wt; const float* bias;
  const int* deg; const float* wf; const float* bf; float* zout; int M; int lb;
  if (bid < gbC) {
    accb = accC; wt = wtC; bias = b1 + 128; deg = deg1;
    wf = wfC; bf = bfC; zout = zc; M = NCARD; lb = bid;
  } else {
    accb = accI; wt = wtI; bias = b1 + 384; deg = deg3;
    wf = wfI; bf = bfI; zout = zi; M = NIP; lb = bid - gbC;
  }
  int wave = threadIdx.x >> 6, lane = threadIdx.x & 63;
  int q = lane >> 4, cl = lane & 15;
  int r0w = lb * 128 + wave * 32;

  s8v af[2][4];
#pragma unroll
  for (int rt = 0; rt < 2; rt++)
#pragma unroll
    for (int ks = 0; ks < 4; ks++)
      af[rt][ks] = *(const s8v*)(accb + (size_t)(r0w + rt * 16 + cl) * 128 + ks * 32 + q * 8);

  f4v acc[2][8];
#pragma unroll
  for (int rt = 0; rt < 2; rt++)
#pragma unroll
    for (int nt = 0; nt < 8; nt++) acc[rt][nt] = (f4v){0.f, 0.f, 0.f, 0.f};

#pragma unroll
  for (int nt = 0; nt < 8; nt++) {
#pragma unroll
    for (int ks = 0; ks < 4; ks++) {
      s8v bfr = *(const s8v*)(wt + (size_t)(nt * 16 + cl) * 128 + ks * 32 + q * 8);
      acc[0][nt] = __builtin_amdgcn_mfma_f32_16x16x32_bf16(af[0][ks], bfr, acc[0][nt], 0, 0, 0);
      acc[1][nt] = __builtin_amdgcn_mfma_f32_16x16x32_bf16(af[1][ks], bfr, acc[1][nt], 0, 0, 0);
    }
  }

  float2 wfv[8];
  float b1v[8];
#pragma unroll
  for (int nt = 0; nt < 8; nt++) {
    wfv[nt] = ((const float2*)wf)[nt * 16 + cl];
    b1v[nt] = bias[nt * 16 + cl];
  }
  float2 bf2 = *(const float2*)bf;
#pragma unroll
  for (int rt = 0; rt < 2; rt++) {
#pragma unroll
    for (int reg = 0; reg < 4; reg++) {
      int row = r0w + rt * 16 + q * 4 + reg;
      int d = (row < M) ? deg[row] : 0;
      float sc = (d > 0) ? 1.f / (float)d : 0.f;
      float p0 = 0.f, p1 = 0.f;
#pragma unroll
      for (int nt = 0; nt < 8; nt++) {
        float h = 0.f;
        if (d > 0) {
          h = acc[rt][nt][reg] * sc + b1v[nt];
          h = h > 0.f ? h : 0.01f * h;
        }
        p0 += h * wfv[nt].x;
        p1 += h * wfv[nt].y;
      }
#pragma unroll
      for (int o = 1; o < 16; o <<= 1) {
        p0 += __shfl_xor(p0, o);
        p1 += __shfl_xor(p1, o);
      }
      if (cl == 0 && row < M) {
        ((float2*)zout)[row] = make_float2(p0 + bf2.x, p1 + bf2.y);
      }
    }
  }
}

// ------- target-side: CSR gather of z + mean + softmax (no atomics) -------

__global__ void finalg_k(const float* __restrict__ zc, const float* __restrict__ zi,
                         const int* __restrict__ off0, const int* __restrict__ deg0,
                         const int* __restrict__ csr0, const int* __restrict__ off2,
                         const int* __restrict__ deg2, const int* __restrict__ csr2,
                         const float* __restrict__ bout, float* __restrict__ out) {
  int t = blockIdx.x * 256 + threadIdx.x;
  if (t >= NT) return;
  float l0 = bout[0], l1 = bout[1];
  {
    int d = deg0[t], st = off0[t];
    if (d > 0) {
      float ax = 0.f, ay = 0.f;
      for (int i = 0; i < d; i++) {
        float2 z = ((const float2*)zc)[csr0[st + i]];
        ax += z.x; ay += z.y;
      }
      float inv = 1.f / (float)d;
      l0 += ax * inv; l1 += ay * inv;
    }
  }
  {
    int d = deg2[t], st = off2[t];
    if (d > 0) {
      float ax = 0.f, ay = 0.f;
      for (int i = 0; i < d; i++) {
        float2 z = ((const float2*)zi)[csr2[st + i]];
        ax += z.x; ay += z.y;
      }
      float inv = 1.f / (float)d;
      l0 += ax * inv; l1 += ay * inv;
    }
  }
  float m = fmaxf(l0, l1);
  float e0 = expf(l0 - m), e1 = expf(l1 - m);
  float inv = 1.f / (e0 + e1);
  ((float2*)out)[t] = make_float2(e0 * inv, e1 * inv);
}

// ---------------- launch ----------------

extern "C" void kernel_launch(void* const* d_in, const int* in_sizes, int n_in,
                              void* d_out, int out_size, void* d_ws, size_t ws_size,
                              hipStream_t stream) {
  const float* x_target = (const float*)d_in[0];
  const float* w1 = (const float*)d_in[3];
  const float* b1 = (const float*)d_in[4];
  const float* w2 = (const float*)d_in[5];
  const float* b2 = (const float*)d_in[6];
  const float* wout = (const float*)d_in[7];
  const float* bout = (const float*)d_in[8];
  const int* src0 = (const int*)d_in[9];
  const int* dst0 = (const int*)d_in[10];
  const int* src1 = (const int*)d_in[11];
  const int* dst1 = (const int*)d_in[12];
  const int* src2 = (const int*)d_in[13];
  const int* dst2 = (const int*)d_in[14];
  const int* src3 = (const int*)d_in[15];
  const int* dst3 = (const int*)d_in[16];
  float* out = (float*)d_out;

  char* p = (char*)d_ws;
  auto alloc = [&](size_t bytes) -> char* {
    char* r = p;
    p += (bytes + 255) & ~(size_t)255;
    return r;
  };
  int* deg1 = (int*)alloc(NCARD * 4);
  int* deg3 = (int*)alloc(NIP * 4);
  int* deg0 = (int*)alloc(NT * 4);
  int* deg2 = (int*)alloc(NT * 4);
  int* rk1 = (int*)alloc(NE * 4);
  int* rk3 = (int*)alloc(NE * 4);
  int* rk0 = (int*)alloc(NE * 4);
  int* rk2 = (int*)alloc(NE * 4);
  int* off1 = (int*)alloc(NCARD * 4);
  int* off3 = (int*)alloc(NIP * 4);
  int* off0 = (int*)alloc(NT * 4);
  int* off2 = (int*)alloc(NT * 4);
  int* bs1 = (int*)alloc(1024 * 4);
  int* bs3 = (int*)alloc(1024 * 4);
  int* bs0 = (int*)alloc(1024 * 4);
  int* bs2 = (int*)alloc(1024 * 4);
  int* csr1 = (int*)alloc(NE * 4);
  int* csr3 = (int*)alloc(NE * 4);
  int* csr0 = (int*)alloc(NE * 4);
  int* csr2 = (int*)alloc(NE * 4);
  unsigned short* xb = (unsigned short*)alloc((size_t)NT * 128 * 2);
  unsigned short* accC = (unsigned short*)alloc((size_t)NCARD * 128 * 2);
  unsigned short* accI = (unsigned short*)alloc((size_t)NIP * 128 * 2);
  alloc(128 * 128 * 2);  // pad: OOB-row A-fragment reads from the last gemm block
  unsigned short* wtC = (unsigned short*)alloc(16384 * 2);
  unsigned short* wtI = (unsigned short*)alloc(16384 * 2);
  float* zc = (float*)alloc((size_t)NCARD * 2 * 4);
  float* zi = (float*)alloc((size_t)NIP * 2 * 4);
  float* wfC = (float*)alloc(256 * 4);
  float* wfI = (float*)alloc(256 * 4);
  float* bfC = (float*)alloc(2 * 4);
  float* bfI = (float*)alloc(2 * 4);

  // Per-chunk histograms (9.6MB) alias into accC (25.6MB): dead once fill4 completes,
  // and accC is first written by aggf_k, which launches after fill4.
  int* h1 = (int*)accC;
  int* h3 = h1 + (size_t)NCHUNK * NCARD;
  int* h0 = h3 + (size_t)NCHUNK * NIP;
  int* h2 = h0 + (size_t)NCHUNK * NT;

  hist_k<<<NB_HISTA, 256, 0, stream>>>(dst1, dst3, dst0, dst2, h1, h3, h0, h2,
                                       rk1, rk3, rk0, rk2);

  front_k<<<NB_WT + 1 + NB_CVT, 256, 0, stream>>>(
      x_target, w1, w2, b2, wout, xb, wtC, wtI, wfC, wfI, bfC, bfI);

  int nb1 = (NCARD + 255) / 256, nb3 = (NIP + 255) / 256;
  int nb0 = (NT + 255) / 256, nb2 = (NT + 255) / 256;
  scan1q_k<<<nb1 + nb3 + nb0 + nb2, 256, 0, stream>>>(
      h1, deg1, off1, bs1, nb1, h3, deg3, off3, bs3, nb3,
      h0, deg0, off0, bs0, nb0, h2, deg2, off2, bs2);
  scan2q_k<<<4, 1024, 0, stream>>>(bs1, nb1, bs3, nb3, bs0, nb0, bs2, nb2);
  scan3q_k<<<nb1 + nb3 + nb0 + nb2, 256, 0, stream>>>(
      off1, bs1, nb1, off3, bs3, nb3, off0, bs0, nb0, off2, bs2);

  fill4_k<<<(4 * NE + 255) / 256, 256, 0, stream>>>(
      src1, dst1, rk1, off1, h1, csr1, src3, dst3, rk3, off3, h3, csr3,
      src0, dst0, rk0, off0, h0, csr0, src2, dst2, rk2, off2, h2, csr2);

  aggf_k<<<(NCARD + NIP + 3) / 4, 256, 0, stream>>>(xb, off1, deg1, csr1, accC,
                                                    off3, deg3, csr3, accI);

  int gbC = (NCARD + 127) / 128, gbI = (NIP + 127) / 128;
  gemm_mfma_k<<<gbC + gbI, 256, 0, stream>>>(accC, accI, wtC, wtI, b1, deg1, deg3,
                                             wfC, wfI, bfC, bfI, zc, zi, gbC);

  finalg_k<<<(NT + 255) / 256, 256, 0, stream>>>(zc, zi, off0, deg0, csr0,
                                                 off2, deg2, csr2, bout, out);
}

// Round 3
// 412.427 us; speedup vs baseline: 1.2480x; 1.2480x over previous
//
#include <hip/hip_runtime.h>

// HeteroRGCN forward, MI355X. Structure (rounds 1-7):
//  - Only h2["target"] matters => layer1 etypes 1,3; layer2 etypes 0,2. x_card/x_ip dead.
//  - Layer1 aggregate-first; layer2+output folded to Wfold=W2@wout (2 cols/node).
//  - bf16 storage + MFMA 16x16x32 for the 128x128 transform; fp32 accumulate.
//  - Round 5-6: partitioned LDS histogram CSR build (zero global atomics), own kernel.
//  - Round 7: hist was latency-bound (304 blocks, serial scalar loads -> 130us, 13% occ).
//    Fix: NCHUNK 4->8 (608 blocks) + int4 edge loads (ILP 4) + vector init/writeback.
//    aggf: cooperative 64-wide CSR index preload + shfl broadcast (kills per-edge
//    dependent-load chain). fill4: int4 x4-edge threads. scan3q folded into consumers
//    (slot base = off[n] + bs[n>>8]).

#define NT 200000
#define NCARD 100000
#define NIP 100000
#define NE 300000

#define RANGE 8192       // bins per hist block (32KB LDS)
#define NCHUNK 8
#define CHUNK 37500      // NE / NCHUNK
#define CHUNK4 9375      // CHUNK / 4
#define RB1 13           // ceil(NCARD/RANGE)
#define RB3 13
#define RB0 25           // ceil(NT/RANGE)
#define RB2 25
#define NB_HISTA ((RB1 + RB3 + RB0 + RB2) * NCHUNK)  // 608

typedef __attribute__((ext_vector_type(8))) short s8v;   // 8 bf16 (4 VGPRs)
typedef __attribute__((ext_vector_type(4))) float f4v;   // mfma accumulator

__device__ __forceinline__ unsigned short f2b(float f) {
  unsigned u = __float_as_uint(f);
  u = (u + 0x7fff + ((u >> 16) & 1)) >> 16;  // RNE (finite inputs)
  return (unsigned short)u;
}

// ---------------- LDS histogram + per-edge rank (4 relations x NCHUNK chunks) ----------------
// Each block: one 8192-bin dst range x one edge chunk. int4 edge loads for 4-deep MLP;
// dst arrays are 4.8MB total -> L2-resident across the RB-fold re-reads.

__global__ __launch_bounds__(256) void hist_k(
    const int* __restrict__ d1, const int* __restrict__ d3,
    const int* __restrict__ d0, const int* __restrict__ d2,
    int* __restrict__ h1, int* __restrict__ h3,
    int* __restrict__ h0, int* __restrict__ h2,
    int* __restrict__ rk1, int* __restrict__ rk3,
    int* __restrict__ rk0, int* __restrict__ rk2) {
  __shared__ int hsh[RANGE];
  int tid = threadIdx.x;
  int rb = blockIdx.x / NCHUNK, c = blockIdx.x % NCHUNK;
  const int* d; int* hist; int* rkl; int N; int lo;
  if (rb < RB1) { d = d1; hist = h1; rkl = rk1; N = NCARD; lo = rb * RANGE; }
  else if (rb < RB1 + RB3) { d = d3; hist = h3; rkl = rk3; N = NIP; lo = (rb - RB1) * RANGE; }
  else if (rb < RB1 + RB3 + RB0) { d = d0; hist = h0; rkl = rk0; N = NT; lo = (rb - RB1 - RB3) * RANGE; }
  else { d = d2; hist = h2; rkl = rk2; N = NT; lo = (rb - RB1 - RB3 - RB0) * RANGE; }
  int4* h4 = (int4*)hsh;
  for (int b = tid; b < RANGE / 4; b += 256) h4[b] = make_int4(0, 0, 0, 0);
  __syncthreads();
  const int4* d4 = (const int4*)d + (size_t)c * CHUNK4;
  int ebase = c * CHUNK;
  for (int i = tid; i < CHUNK4; i += 256) {
    int4 v = d4[i];
    int e = ebase + i * 4;
    int k0 = v.x - lo, k1 = v.y - lo, k2 = v.z - lo, k3 = v.w - lo;
    if ((unsigned)k0 < (unsigned)RANGE) rkl[e] = atomicAdd(&hsh[k0], 1);
    if ((unsigned)k1 < (unsigned)RANGE) rkl[e + 1] = atomicAdd(&hsh[k1], 1);
    if ((unsigned)k2 < (unsigned)RANGE) rkl[e + 2] = atomicAdd(&hsh[k2], 1);
    if ((unsigned)k3 < (unsigned)RANGE) rkl[e + 3] = atomicAdd(&hsh[k3], 1);
  }
  __syncthreads();
  int n4 = (min(RANGE, N - lo)) >> 2;  // N%4==0, lo%4==0
  int4* hist4 = (int4*)(hist + (size_t)c * N + lo);
  for (int b = tid; b < n4; b += 256) hist4[b] = h4[b];
}

// ---------------- fused front: W1 transpose | Wfold prep | cvt (LDS-free streaming) ----------
// Block ranges: [0,128) wt, [128] prep, [129,12629) cvt (2 float4/thread).

#define NB_WT 128
#define NB_CVT 12500     // NT*128/4 float4s / 512 per block

__global__ void front_k(const float* __restrict__ x, const float* __restrict__ w1,
                        const float* __restrict__ w2, const float* __restrict__ b2,
                        const float* __restrict__ wout,
                        unsigned short* __restrict__ xb, unsigned short* __restrict__ wtC,
                        unsigned short* __restrict__ wtI, float* __restrict__ wfC,
                        float* __restrict__ wfI, float* __restrict__ bfC,
                        float* __restrict__ bfI) {
  int bid = blockIdx.x, tid = threadIdx.x;
  if (bid < NB_WT) {
    int t = bid * 256 + tid;  // 32768
    int r = t >> 14;
    int n = (t >> 7) & 127, k = t & 127;
    const float* src = w1 + (r ? 3 : 1) * 16384;
    unsigned short* dst = r ? wtI : wtC;
    dst[n * 128 + k] = f2b(src[k * 128 + n]);
  } else if (bid == NB_WT) {
    int k = tid >> 1, o = tid & 1;
    float sC = 0.f, sI = 0.f;
    for (int j = 0; j < 128; j++) {
      float wo = wout[j * 2 + o];
      sC += w2[0 * 16384 + k * 128 + j] * wo;
      sI += w2[2 * 16384 + k * 128 + j] * wo;
    }
    wfC[k * 2 + o] = sC;
    wfI[k * 2 + o] = sI;
    if (tid < 2) {
      float s = 0.f;
      for (int j = 0; j < 128; j++) s += b2[0 * 128 + j] * wout[j * 2 + tid];
      bfC[tid] = s;
    } else if (tid < 4) {
      int oo = tid - 2;
      float s = 0.f;
      for (int j = 0; j < 128; j++) s += b2[2 * 128 + j] * wout[j * 2 + oo];
      bfI[oo] = s;
    }
  } else {
    long i = (long)(bid - (NB_WT + 1)) * 512 + tid;  // two float4 each
    const float4* x4 = (const float4*)x;
    float4 va = x4[i];
    float4 vb = x4[i + 256];
    uint2 oa, ob;
    oa.x = (unsigned)f2b(va.x) | ((unsigned)f2b(va.y) << 16);
    oa.y = (unsigned)f2b(va.z) | ((unsigned)f2b(va.w) << 16);
    ob.x = (unsigned)f2b(vb.x) | ((unsigned)f2b(vb.y) << 16);
    ob.y = (unsigned)f2b(vb.z) | ((unsigned)f2b(vb.w) << 16);
    ((uint2*)xb)[i] = oa;
    ((uint2*)xb)[i + 256] = ob;
  }
}

// -------- scans: fold per-chunk hist -> (deg, chunk-exclusive prefix), then block scan -------
// off stays block-local-exclusive; consumers add bs[node>>8] (scan3 eliminated).

__global__ void scan1q_k(int* __restrict__ h1, int* __restrict__ deg1,
                         int* __restrict__ off1, int* __restrict__ bs1, int nb1,
                         int* __restrict__ h3, int* __restrict__ deg3,
                         int* __restrict__ off3, int* __restrict__ bs3, int nb3,
                         int* __restrict__ h0, int* __restrict__ deg0,
                         int* __restrict__ off0, int* __restrict__ bs0, int nb0,
                         int* __restrict__ h2, int* __restrict__ deg2,
                         int* __restrict__ off2, int* __restrict__ bs2) {
  __shared__ int s[256];
  int bid = blockIdx.x;
  int* hist; int* deg; int* off; int* bsum; int N; int lb;
  if (bid < nb1) { hist = h1; deg = deg1; off = off1; bsum = bs1; N = NCARD; lb = bid; }
  else if (bid < nb1 + nb3) { hist = h3; deg = deg3; off = off3; bsum = bs3; N = NIP; lb = bid - nb1; }
  else if (bid < nb1 + nb3 + nb0) { hist = h0; deg = deg0; off = off0; bsum = bs0; N = NT; lb = bid - nb1 - nb3; }
  else { hist = h2; deg = deg2; off = off2; bsum = bs2; N = NT; lb = bid - nb1 - nb3 - nb0; }
  int tid = threadIdx.x;
  int i = lb * 256 + tid;
  int v = 0;
  if (i < N) {
    int acc = 0;
#pragma unroll
    for (int c = 0; c < NCHUNK; c++) {
      size_t idx = (size_t)c * N + i;
      int t = hist[idx];
      hist[idx] = acc;  // chunk-exclusive prefix for fill
      acc += t;
    }
    deg[i] = acc;
    v = acc;
  }
  s[tid] = v;
  __syncthreads();
  for (int o = 1; o < 256; o <<= 1) {
    int t = (tid >= o) ? s[tid - o] : 0;
    __syncthreads();
    s[tid] += t;
    __syncthreads();
  }
  if (i < N) off[i] = s[tid] - v;
  if (tid == 255) bsum[lb] = s[255];
}

__global__ void scan2q_k(int* __restrict__ bs1, int nb1, int* __restrict__ bs3, int nb3,
                         int* __restrict__ bs0, int nb0, int* __restrict__ bs2, int nb2) {
  __shared__ int s[1024];
  int* bs; int nb;
  if (blockIdx.x == 0) { bs = bs1; nb = nb1; }
  else if (blockIdx.x == 1) { bs = bs3; nb = nb3; }
  else if (blockIdx.x == 2) { bs = bs0; nb = nb0; }
  else { bs = bs2; nb = nb2; }
  int t = threadIdx.x;
  int v = (t < nb) ? bs[t] : 0;
  s[t] = v;
  __syncthreads();
  for (int o = 1; o < 1024; o <<= 1) {
    int u = (t >= o) ? s[t - o] : 0;
    __syncthreads();
    s[t] += u;
    __syncthreads();
  }
  if (t < nb) bs[t] = s[t] - v;
}

// ------- atomic-free CSR fill: slot = off[dst]+bs[dst>>8] + chunkpref[c][dst] + rank_local ---
// int4: each thread owns 4 consecutive edges of one relation (8 gathers + 4 scatters in flight).

#define T4 75000  // NE/4

__global__ void fill4_k(const int* __restrict__ s1, const int* __restrict__ d1,
                        const int* __restrict__ rk1, const int* __restrict__ off1,
                        const int* __restrict__ bs1, const int* __restrict__ h1,
                        int* __restrict__ csr1,
                        const int* __restrict__ s3, const int* __restrict__ d3,
                        const int* __restrict__ rk3, const int* __restrict__ off3,
                        const int* __restrict__ bs3, const int* __restrict__ h3,
                        int* __restrict__ csr3,
                        const int* __restrict__ s0, const int* __restrict__ d0,
                        const int* __restrict__ rk0, const int* __restrict__ off0,
                        const int* __restrict__ bs0, const int* __restrict__ h0,
                        int* __restrict__ csr0,
                        const int* __restrict__ s2, const int* __restrict__ d2,
                        const int* __restrict__ rk2, const int* __restrict__ off2,
                        const int* __restrict__ bs2, const int* __restrict__ h2,
                        int* __restrict__ csr2) {
  int t = blockIdx.x * 256 + threadIdx.x;
  const int* s; const int* d; const int* rk; const int* off; const int* bs;
  const int* h; int* csr; int N; int e4;
  if (t < T4) { s = s1; d = d1; rk = rk1; off = off1; bs = bs1; h = h1; csr = csr1; N = NCARD; e4 = t; }
  else if (t < 2 * T4) { s = s3; d = d3; rk = rk3; off = off3; bs = bs3; h = h3; csr = csr3; N = NIP; e4 = t - T4; }
  else if (t < 3 * T4) { s = s0; d = d0; rk = rk0; off = off0; bs = bs0; h = h0; csr = csr0; N = NT; e4 = t - 2 * T4; }
  else if (t < 4 * T4) { s = s2; d = d2; rk = rk2; off = off2; bs = bs2; h = h2; csr = csr2; N = NT; e4 = t - 3 * T4; }
  else return;
  int4 dv = ((const int4*)d)[e4];
  int4 rv = ((const int4*)rk)[e4];
  int4 sv = ((const int4*)s)[e4];
  int c = e4 / CHUNK4;  // 4-edge group never straddles a chunk (CHUNK%4==0)
  const int* hc = h + (size_t)c * N;
  csr[off[dv.x] + bs[dv.x >> 8] + hc[dv.x] + rv.x] = sv.x;
  csr[off[dv.y] + bs[dv.y >> 8] + hc[dv.y] + rv.y] = sv.y;
  csr[off[dv.z] + bs[dv.z >> 8] + hc[dv.z] + rv.z] = sv.z;
  csr[off[dv.w] + bs[dv.w >> 8] + hc[dv.w] + rv.w] = sv.w;
}

// ------- layer1 source aggregation: one wave per dst row -------
// Cooperative 64-wide CSR index preload (one coalesced load), shfl broadcast to the
// 4 edge-groups x 16 feature-lanes; gathers then issue back-to-back (no index chain).

__global__ void aggf_k(const unsigned short* __restrict__ xb,
                       const int* __restrict__ off1, const int* __restrict__ deg1,
                       const int* __restrict__ bs1, const int* __restrict__ csr1,
                       unsigned short* __restrict__ accC,
                       const int* __restrict__ off3, const int* __restrict__ deg3,
                       const int* __restrict__ bs3, const int* __restrict__ csr3,
                       unsigned short* __restrict__ accI) {
  int w = (blockIdx.x * 256 + threadIdx.x) >> 6;
  int lane = threadIdx.x & 63;
  if (w >= NCARD + NIP) return;
  const int* off; const int* deg; const int* bs; const int* csr;
  unsigned short* acc; int row;
  if (w < NCARD) { off = off1; deg = deg1; bs = bs1; csr = csr1; acc = accC; row = w; }
  else { off = off3; deg = deg3; bs = bs3; csr = csr3; acc = accI; row = w - NCARD; }
  int start = off[row] + bs[row >> 8], cnt = deg[row];
  int eg = lane >> 4, fl = lane & 15;
  int cl = cnt < 64 ? cnt : 64;
  int idx = (lane < cl) ? csr[start + lane] : 0;
  float a[8] = {0.f, 0.f, 0.f, 0.f, 0.f, 0.f, 0.f, 0.f};
  for (int i = eg; i < cl; i += 4) {
    int sidx = __shfl(idx, i);
    uint4 v = *(const uint4*)(xb + (size_t)sidx * 128 + fl * 8);
    a[0] += __uint_as_float(v.x << 16);
    a[1] += __uint_as_float(v.x & 0xffff0000u);
    a[2] += __uint_as_float(v.y << 16);
    a[3] += __uint_as_float(v.y & 0xffff0000u);
    a[4] += __uint_as_float(v.z << 16);
    a[5] += __uint_as_float(v.z & 0xffff0000u);
    a[6] += __uint_as_float(v.w << 16);
    a[7] += __uint_as_float(v.w & 0xffff0000u);
  }
  for (int i = 64 + eg; i < cnt; i += 4) {  // rare: deg > 64
    int sidx = csr[start + i];
    uint4 v = *(const uint4*)(xb + (size_t)sidx * 128 + fl * 8);
    a[0] += __uint_as_float(v.x << 16);
    a[1] += __uint_as_float(v.x & 0xffff0000u);
    a[2] += __uint_as_float(v.y << 16);
    a[3] += __uint_as_float(v.y & 0xffff0000u);
    a[4] += __uint_as_float(v.z << 16);
    a[5] += __uint_as_float(v.z & 0xffff0000u);
    a[6] += __uint_as_float(v.w << 16);
    a[7] += __uint_as_float(v.w & 0xffff0000u);
  }
#pragma unroll
  for (int j = 0; j < 8; j++) {
    a[j] += __shfl_xor(a[j], 16);
    a[j] += __shfl_xor(a[j], 32);
  }
  if (eg == 0) {
    uint4 o;
    o.x = (unsigned)f2b(a[0]) | ((unsigned)f2b(a[1]) << 16);
    o.y = (unsigned)f2b(a[2]) | ((unsigned)f2b(a[3]) << 16);
    o.z = (unsigned)f2b(a[4]) | ((unsigned)f2b(a[5]) << 16);
    o.w = (unsigned)f2b(a[6]) | ((unsigned)f2b(a[7]) << 16);
    *(uint4*)(acc + (size_t)row * 128 + fl * 8) = o;
  }
}

// ------- layer1 transform via MFMA + leaky + fold-to-z epilogue -------
// Per wave: 32 rows x 128 cols, K=128. C/D layout: col=lane&15, row=(lane>>4)*4+reg.
// A layout: A[m=lane&15][k=(lane>>4)*8+j].

__global__ __launch_bounds__(256) void gemm_mfma_k(
    const unsigned short* __restrict__ accC, const unsigned short* __restrict__ accI,
    const unsigned short* __restrict__ wtC, const unsigned short* __restrict__ wtI,
    const float* __restrict__ b1, const int* __restrict__ deg1,
    const int* __restrict__ deg3, const float* __restrict__ wfC,
    const float* __restrict__ wfI, const float* __restrict__ bfC,
    const float* __restrict__ bfI, float* __restrict__ zc, float* __restrict__ zi,
    int gbC) {
  int bid = blockIdx.x;
  const unsigned short* accb; const unsigned short* wt; const float* bias;
  const int* deg; const float* wf; const float* bf; float* zout; int M; int lb;
  if (bid < gbC) {
    accb = accC; wt = wtC; bias = b1 + 128; deg = deg1;
    wf = wfC; bf = bfC; zout = zc; M = NCARD; lb = bid;
  } else {
    accb = accI; wt = wtI; bias = b1 + 384; deg = deg3;
    wf = wfI; bf = bfI; zout = zi; M = NIP; lb = bid - gbC;
  }
  int wave = threadIdx.x >> 6, lane = threadIdx.x & 63;
  int q = lane >> 4, cl = lane & 15;
  int r0w = lb * 128 + wave * 32;

  s8v af[2][4];
#pragma unroll
  for (int rt = 0; rt < 2; rt++)
#pragma unroll
    for (int ks = 0; ks < 4; ks++)
      af[rt][ks] = *(const s8v*)(accb + (size_t)(r0w + rt * 16 + cl) * 128 + ks * 32 + q * 8);

  f4v acc[2][8];
#pragma unroll
  for (int rt = 0; rt < 2; rt++)
#pragma unroll
    for (int nt = 0; nt < 8; nt++) acc[rt][nt] = (f4v){0.f, 0.f, 0.f, 0.f};

#pragma unroll
  for (int nt = 0; nt < 8; nt++) {
#pragma unroll
    for (int ks = 0; ks < 4; ks++) {
      s8v bfr = *(const s8v*)(wt + (size_t)(nt * 16 + cl) * 128 + ks * 32 + q * 8);
      acc[0][nt] = __builtin_amdgcn_mfma_f32_16x16x32_bf16(af[0][ks], bfr, acc[0][nt], 0, 0, 0);
      acc[1][nt] = __builtin_amdgcn_mfma_f32_16x16x32_bf16(af[1][ks], bfr, acc[1][nt], 0, 0, 0);
    }
  }

  float2 wfv[8];
  float b1v[8];
#pragma unroll
  for (int nt = 0; nt < 8; nt++) {
    wfv[nt] = ((const float2*)wf)[nt * 16 + cl];
    b1v[nt] = bias[nt * 16 + cl];
  }
  float2 bf2 = *(const float2*)bf;
#pragma unroll
  for (int rt = 0; rt < 2; rt++) {
#pragma unroll
    for (int reg = 0; reg < 4; reg++) {
      int row = r0w + rt * 16 + q * 4 + reg;
      int d = (row < M) ? deg[row] : 0;
      float sc = (d > 0) ? 1.f / (float)d : 0.f;
      float p0 = 0.f, p1 = 0.f;
#pragma unroll
      for (int nt = 0; nt < 8; nt++) {
        float h = 0.f;
        if (d > 0) {
          h = acc[rt][nt][reg] * sc + b1v[nt];
          h = h > 0.f ? h : 0.01f * h;
        }
        p0 += h * wfv[nt].x;
        p1 += h * wfv[nt].y;
      }
#pragma unroll
      for (int o = 1; o < 16; o <<= 1) {
        p0 += __shfl_xor(p0, o);
        p1 += __shfl_xor(p1, o);
      }
      if (cl == 0 && row < M) {
        ((float2*)zout)[row] = make_float2(p0 + bf2.x, p1 + bf2.y);
      }
    }
  }
}

// ------- target-side: CSR gather of z + mean + softmax (no atomics) -------

__global__ void finalg_k(const float* __restrict__ zc, const float* __restrict__ zi,
                         const int* __restrict__ off0, const int* __restrict__ deg0,
                         const int* __restrict__ bs0, const int* __restrict__ csr0,
                         const int* __restrict__ off2, const int* __restrict__ deg2,
                         const int* __restrict__ bs2, const int* __restrict__ csr2,
                         const float* __restrict__ bout, float* __restrict__ out) {
  int t = blockIdx.x * 256 + threadIdx.x;
  if (t >= NT) return;
  int d0 = deg0[t], st0 = off0[t] + bs0[t >> 8];
  int d2 = deg2[t], st2 = off2[t] + bs2[t >> 8];
  float l0 = bout[0], l1 = bout[1];
  if (d0 > 0) {
    float ax = 0.f, ay = 0.f;
    for (int i = 0; i < d0; i++) {
      float2 z = ((const float2*)zc)[csr0[st0 + i]];
      ax += z.x; ay += z.y;
    }
    float inv = 1.f / (float)d0;
    l0 += ax * inv; l1 += ay * inv;
  }
  if (d2 > 0) {
    float ax = 0.f, ay = 0.f;
    for (int i = 0; i < d2; i++) {
      float2 z = ((const float2*)zi)[csr2[st2 + i]];
      ax += z.x; ay += z.y;
    }
    float inv = 1.f / (float)d2;
    l0 += ax * inv; l1 += ay * inv;
  }
  float m = fmaxf(l0, l1);
  float e0 = expf(l0 - m), e1 = expf(l1 - m);
  float inv = 1.f / (e0 + e1);
  ((float2*)out)[t] = make_float2(e0 * inv, e1 * inv);
}

// ---------------- launch ----------------

extern "C" void kernel_launch(void* const* d_in, const int* in_sizes, int n_in,
                              void* d_out, int out_size, void* d_ws, size_t ws_size,
                              hipStream_t stream) {
  const float* x_target = (const float*)d_in[0];
  const float* w1 = (const float*)d_in[3];
  const float* b1 = (const float*)d_in[4];
  const float* w2 = (const float*)d_in[5];
  const float* b2 = (const float*)d_in[6];
  const float* wout = (const float*)d_in[7];
  const float* bout = (const float*)d_in[8];
  const int* src0 = (const int*)d_in[9];
  const int* dst0 = (const int*)d_in[10];
  const int* src1 = (const int*)d_in[11];
  const int* dst1 = (const int*)d_in[12];
  const int* src2 = (const int*)d_in[13];
  const int* dst2 = (const int*)d_in[14];
  const int* src3 = (const int*)d_in[15];
  const int* dst3 = (const int*)d_in[16];
  float* out = (float*)d_out;

  char* p = (char*)d_ws;
  auto alloc = [&](size_t bytes) -> char* {
    char* r = p;
    p += (bytes + 255) & ~(size_t)255;
    return r;
  };
  int* deg1 = (int*)alloc(NCARD * 4);
  int* deg3 = (int*)alloc(NIP * 4);
  int* deg0 = (int*)alloc(NT * 4);
  int* deg2 = (int*)alloc(NT * 4);
  int* rk1 = (int*)alloc(NE * 4);
  int* rk3 = (int*)alloc(NE * 4);
  int* rk0 = (int*)alloc(NE * 4);
  int* rk2 = (int*)alloc(NE * 4);
  int* off1 = (int*)alloc(NCARD * 4);
  int* off3 = (int*)alloc(NIP * 4);
  int* off0 = (int*)alloc(NT * 4);
  int* off2 = (int*)alloc(NT * 4);
  int* bs1 = (int*)alloc(1024 * 4);
  int* bs3 = (int*)alloc(1024 * 4);
  int* bs0 = (int*)alloc(1024 * 4);
  int* bs2 = (int*)alloc(1024 * 4);
  int* csr1 = (int*)alloc(NE * 4);
  int* csr3 = (int*)alloc(NE * 4);
  int* csr0 = (int*)alloc(NE * 4);
  int* csr2 = (int*)alloc(NE * 4);
  unsigned short* xb = (unsigned short*)alloc((size_t)NT * 128 * 2);
  unsigned short* accC = (unsigned short*)alloc((size_t)NCARD * 128 * 2);
  unsigned short* accI = (unsigned short*)alloc((size_t)NIP * 128 * 2);
  alloc(128 * 128 * 2);  // pad: OOB-row A-fragment reads from the last gemm block
  unsigned short* wtC = (unsigned short*)alloc(16384 * 2);
  unsigned short* wtI = (unsigned short*)alloc(16384 * 2);
  float* zc = (float*)alloc((size_t)NCARD * 2 * 4);
  float* zi = (float*)alloc((size_t)NIP * 2 * 4);
  float* wfC = (float*)alloc(256 * 4);
  float* wfI = (float*)alloc(256 * 4);
  float* bfC = (float*)alloc(2 * 4);
  float* bfI = (float*)alloc(2 * 4);

  // Per-chunk histograms (NCHUNK * 600K ints = 19.2MB) alias into accC (25.6MB): dead once
  // fill4 completes; accC is first written by aggf_k, which launches after fill4.
  int* h1 = (int*)accC;
  int* h3 = h1 + (size_t)NCHUNK * NCARD;
  int* h0 = h3 + (size_t)NCHUNK * NIP;
  int* h2 = h0 + (size_t)NCHUNK * NT;

  hist_k<<<NB_HISTA, 256, 0, stream>>>(dst1, dst3, dst0, dst2, h1, h3, h0, h2,
                                       rk1, rk3, rk0, rk2);

  front_k<<<NB_WT + 1 + NB_CVT, 256, 0, stream>>>(
      x_target, w1, w2, b2, wout, xb, wtC, wtI, wfC, wfI, bfC, bfI);

  int nb1 = (NCARD + 255) / 256, nb3 = (NIP + 255) / 256;
  int nb0 = (NT + 255) / 256, nb2 = (NT + 255) / 256;
  scan1q_k<<<nb1 + nb3 + nb0 + nb2, 256, 0, stream>>>(
      h1, deg1, off1, bs1, nb1, h3, deg3, off3, bs3, nb3,
      h0, deg0, off0, bs0, nb0, h2, deg2, off2, bs2);
  scan2q_k<<<4, 1024, 0, stream>>>(bs1, nb1, bs3, nb3, bs0, nb0, bs2, nb2);

  fill4_k<<<(4 * T4 + 255) / 256, 256, 0, stream>>>(
      src1, dst1, rk1, off1, bs1, h1, csr1, src3, dst3, rk3, off3, bs3, h3, csr3,
      src0, dst0, rk0, off0, bs0, h0, csr0, src2, dst2, rk2, off2, bs2, h2, csr2);

  aggf_k<<<(NCARD + NIP + 3) / 4, 256, 0, stream>>>(
      xb, off1, deg1, bs1, csr1, accC, off3, deg3, bs3, csr3, accI);

  int gbC = (NCARD + 127) / 128, gbI = (NIP + 127) / 128;
  gemm_mfma_k<<<gbC + gbI, 256, 0, stream>>>(accC, accI, wtC, wtI, b1, deg1, deg3,
                                             wfC, wfI, bfC, bfI, zc, zi, gbC);

  finalg_k<<<(NT + 255) / 256, 256, 0, stream>>>(zc, zi, off0, deg0, bs0, csr0,
                                                 off2, deg2, bs2, csr2, bout, out);
}